// Round 11
// baseline (26.914 us; speedup 1.0000x reference)
//
#include <hip/hip_runtime.h>
#include <hip/hip_bf16.h>

#define N_X    65536
#define N_IND  1024
#define N_DESC 64
#define NCHUNK 2
#define CROWS  (N_IND / NCHUNK)   // 512 z-rows per chunk
#define TILES  (CROWS / 16)       // 32 MFMA row-tiles per chunk
#define L2E    1.4426950408889634f
#define L2E2   2.8853900817779268f

typedef __attribute__((ext_vector_type(8))) short  short8;
typedef __attribute__((ext_vector_type(4))) float  f32x4;
typedef __attribute__((ext_vector_type(2))) float  f32x2;

static __device__ __forceinline__ ushort f2bf(float f) {
    union { float f; unsigned u; } a; a.f = f;
    unsigned r = a.u + 0x7FFF + ((a.u >> 16) & 1);   // RNE to bf16
    return (ushort)(r >> 16);
}
static __device__ __forceinline__ float bf2f(ushort h) {
    union { unsigned u; float f; } a; a.u = (unsigned)h << 16;
    return a.f;
}

// ---------------------------------------------------------------------------
// Round 11: occupancy play. 1024-thr blocks (16 waves) over a HALF-panel
// (512 z-rows -> 69 KB LDS) with S=1 strip/wave and a hard 64-VGPR cap
// (__launch_bounds__(1024, 8)) -> 2 blocks/CU = 32 waves/CU = 8 waves/SIMD.
// R10 showed LDS traffic isn't the wall (2.7x cut, ~0 gain): at 4 waves/SIMD
// the per-tile chain serializes the LDS/VALU/trans/MFMA pipes. 8 waves/SIMD
// at mixed phases overlaps them; target = max(pipe) ~ 8.5 us, not sum.
// Keeps R10's proven pieces: operand swap (mfma(x_frag, z_frag): D row =
// x-col = 4g+reg, D col = z-row = p; epilogue constants = ONE float2
// ds_read_b64/tile), XOR-swizzled panel (byte colb ^= (row&7)<<4 both
// sides), in-register x->bf16 conversion, part[] + reduce for the 2 chunks.
// Design VGPR ~50 (b-frags 8, acc 4, xs2 4, addr 2, temps ~20) -> the 64
// cap has slack; no spill expected (watch WRITE_SIZE).
// ---------------------------------------------------------------------------
__global__ __launch_bounds__(1024, 8) void igpr_fused(
        const float* __restrict__ x, const float* __restrict__ z,
        const float* __restrict__ alpha, const float* __restrict__ ls,
        float* __restrict__ part) {
    struct SM {
        uint4  zt[CROWS * 8];    // 512 rows * 128 B = 64 KB (swizzled)
        float2 za[CROWS];        // {log2e*||zw||^2, alpha}  (4 KB)
        float  xs2a[16 * 16];    // per-wave xs2 redistribution (1 KB)
        float  wls[N_DESC];      // exp(-ls/2)
    };
    __shared__ SM sm;            // 69.25 KB -> 2 blocks/CU

    const int tid  = threadIdx.x;
    const int lane = tid & 63;
    const int wave = tid >> 6;                    // 0..15
    const int p = lane & 15;                      // z-row within tile (D col)
    const int g = lane >> 4;                      // k-group; D rows 4g..4g+3
    const int j0 = blockIdx.x * 256 + wave * 16;  // wave's 16 x-cols
    const int c  = blockIdx.y;                    // z-chunk

    if (tid < N_DESC) sm.wls[tid] = __expf(-0.5f * ls[tid]);
    __syncthreads();   // wls ready

    // ---- stage half z-panel (f32 -> weighted bf16, swizzled) + za ----
    {
        const float* zc = z + (size_t)c * CROWS * N_DESC;
        char* zbw = reinterpret_cast<char*>(sm.zt);
#pragma unroll
        for (int rb = 0; rb < 4; ++rb) {
            int lb  = rb * 1024 + tid;       // 16B-granule index (4096 total)
            int row = lb >> 3, gr = lb & 7;  // local z-row, granule in row
            float4 v0 = *reinterpret_cast<const float4*>(&zc[row * 64 + gr * 8]);
            float4 v1 = *reinterpret_cast<const float4*>(&zc[row * 64 + gr * 8 + 4]);
            float vv[8] = {v0.x, v0.y, v0.z, v0.w, v1.x, v1.y, v1.z, v1.w};
            ushort hb[8];
            float sq = 0.f;
#pragma unroll
            for (int e = 0; e < 8; ++e) {
                ushort h = f2bf(vv[e] * sm.wls[gr * 8 + e]);
                hb[e] = h;
                float vr = bf2f(h);
                sq = fmaf(vr, vr, sq);
            }
            uint4 u = make_uint4(
                (unsigned)hb[0] | ((unsigned)hb[1] << 16),
                (unsigned)hb[2] | ((unsigned)hb[3] << 16),
                (unsigned)hb[4] | ((unsigned)hb[5] << 16),
                (unsigned)hb[6] | ((unsigned)hb[7] << 16));
            int sw = row * 128 + ((gr * 16) ^ ((row & 7) << 4));
            *reinterpret_cast<uint4*>(zbw + sw) = u;
            // row-sum over the 8 granule-lanes (tid bits 0..2)
            sq += __shfl_xor(sq, 1);
            sq += __shfl_xor(sq, 2);
            sq += __shfl_xor(sq, 4);
            if (gr == 0) {
                float2 zv; zv.x = sq * L2E; zv.y = alpha[c * CROWS + row];
                sm.za[row] = zv;
            }
        }
    }

    // ---- x fragment: 1 strip of 16 cols (x clean, converted in-reg) ----
    short8 b0, b1;
    {
        const float* xr = x + (size_t)(j0 + p) * N_DESC;
        float sq = 0.f;
        short8 bb[2];
#pragma unroll
        for (int h = 0; h < 2; ++h) {
            float4 v0 = *reinterpret_cast<const float4*>(xr + h * 32 + g * 8);
            float4 v1 = *reinterpret_cast<const float4*>(xr + h * 32 + g * 8 + 4);
            float vv[8] = {v0.x, v0.y, v0.z, v0.w, v1.x, v1.y, v1.z, v1.w};
#pragma unroll
            for (int e = 0; e < 8; ++e) {
                ushort hh = f2bf(vv[e] * sm.wls[h * 32 + g * 8 + e]);
                bb[h][e] = (short)hh;
                float xv = bf2f(hh);
                sq = fmaf(xv, xv, sq);
            }
        }
        b0 = bb[0]; b1 = bb[1];
        sq += __shfl_xor(sq, 16);   // full ||xw||^2 over k-groups
        sq += __shfl_xor(sq, 32);
        if (lane < 16) sm.xs2a[wave * 16 + p] = sq * L2E;
    }

    __syncthreads();   // z-panel, za, xs2a ready (LDS read-only now)

    // xs2 for the 4 x-cols this lane owns after the swap (rows 4g..4g+3)
    f32x2 xs2p[2];
    {
        float4 v = *reinterpret_cast<const float4*>(&sm.xs2a[wave * 16 + 4 * g]);
        f32x2 lo; lo.x = v.x; lo.y = v.y;
        f32x2 hi; hi.x = v.z; hi.y = v.w;
        xs2p[0] = lo; xs2p[1] = hi;
    }

    const char* zb = reinterpret_cast<const char*>(sm.zt);
    const int rb0 = p * 128 + ((16 * g)      ^ ((p & 7) << 4));
    const int rb1 = p * 128 + ((64 + 16 * g) ^ ((p & 7) << 4));

    f32x2 acc2[2] = {{0.f, 0.f}, {0.f, 0.f}};

#pragma unroll 2
    for (int it = 0; it < TILES; ++it) {
        short8 a0 = *reinterpret_cast<const short8*>(zb + it * 2048 + rb0);
        short8 a1 = *reinterpret_cast<const short8*>(zb + it * 2048 + rb1);
        float2 zap = sm.za[it * 16 + p];          // ds_read_b64, conflict-free

        f32x4 t = {0.f, 0.f, 0.f, 0.f};
        t = __builtin_amdgcn_mfma_f32_16x16x32_bf16(b0, a0, t, 0, 0, 0);
        t = __builtin_amdgcn_mfma_f32_16x16x32_bf16(b1, a1, t, 0, 0, 0);

        f32x2 zsp; zsp.x = zap.x; zsp.y = zap.x;  // z2 splat
        f32x2 asp; asp.x = zap.y; asp.y = zap.y;  // alpha splat
#pragma unroll
        for (int w = 0; w < 2; ++w) {
            f32x2 dot2; dot2.x = t[2 * w]; dot2.y = t[2 * w + 1];
            f32x2 zx  = zsp + xs2p[w];              // v_pk_add_f32
            f32x2 arg = dot2 * L2E2 - zx;           // pk_fma (neg mod)
            f32x2 pv; pv.x = __builtin_amdgcn_exp2f(arg.x);
                      pv.y = __builtin_amdgcn_exp2f(arg.y);
            acc2[w] = acc2[w] + asp * pv;           // pk_fma
        }
    }

    // reduce over the 16 p-lanes (z-rows) and write part
    const size_t ob = (size_t)c * N_X;
#pragma unroll
    for (int w = 0; w < 2; ++w)
#pragma unroll
        for (int q = 0; q < 2; ++q) {
            float r = (q == 0) ? acc2[w].x : acc2[w].y;
            r += __shfl_xor(r, 1);
            r += __shfl_xor(r, 2);
            r += __shfl_xor(r, 4);
            r += __shfl_xor(r, 8);
            if (p == 0)
                part[ob + j0 + 4 * g + 2 * w + q] = r;
        }
}

// ---------------------------------------------------------------------------
// reduce: out[j] = part[0][j] + part[1][j]
// ---------------------------------------------------------------------------
__global__ void igpr_reduce(const float* __restrict__ part,
                            float* __restrict__ out) {
    int j = blockIdx.x * 256 + threadIdx.x;
    out[j] = part[j] + part[N_X + j];
}

extern "C" void kernel_launch(void* const* d_in, const int* in_sizes, int n_in,
                              void* d_out, int out_size, void* d_ws, size_t ws_size,
                              hipStream_t stream) {
    const float* x     = (const float*)d_in[0];   // (65536, 64)
    const float* z     = (const float*)d_in[1];   // (1024, 64)
    const float* alpha = (const float*)d_in[2];   // (1024,)
    const float* ls    = (const float*)d_in[3];   // (64,)
    float* out = (float*)d_out;                   // (65536, 1)

    float* part = (float*)d_ws;                   // f32[NCHUNK * N_X]

    igpr_fused<<<dim3(N_X / 256, NCHUNK), dim3(1024), 0, stream>>>(
        x, z, alpha, ls, part);
    igpr_reduce<<<dim3(N_X / 256), dim3(256), 0, stream>>>(part, out);
}

// Round 12
// 24.633 us; speedup vs baseline: 1.0926x; 1.0926x over previous
//
#include <hip/hip_runtime.h>
#include <hip/hip_bf16.h>

#define N_X    65536
#define N_IND  1024
#define N_DESC 64
#define TILES  (N_IND / 16)       // 64 MFMA row-tiles (full z-panel)
#define L2E    1.4426950408889634f
#define L2E2   2.8853900817779268f
#define SKIP_THR (-60.0f)         // 2^-60 * 1024 * |alpha| ~ 4e-15 << tol

typedef __attribute__((ext_vector_type(8))) short  short8;
typedef __attribute__((ext_vector_type(4))) float  f32x4;
typedef __attribute__((ext_vector_type(2))) float  f32x2;

static __device__ __forceinline__ ushort f2bf(float f) {
    union { float f; unsigned u; } a; a.f = f;
    unsigned r = a.u + 0x7FFF + ((a.u >> 16) & 1);   // RNE to bf16
    return (ushort)(r >> 16);
}
static __device__ __forceinline__ float bf2f(ushort h) {
    union { unsigned u; float f; } a; a.u = (unsigned)h << 16;
    return a.f;
}

// ---------------------------------------------------------------------------
// Round 12 = Round 8 (best: 25.45 us, single dispatch, full 128 KB swizzled
// z-panel, 16 waves x S=1) + TILE-LEVEL EXP SKIP:
//   arg[e] = 2*log2e*dot - (z2 + xs2) is computed per tile (cheap pk ops);
//   if ALL 64 lanes have max(arg) < -60 the tile's contribution is < 4e-15
//   (below f32 accumulation granularity and the accepted tolerance) -> skip
//   the alpha read + 4 exp2 + accumulate. With d ~ 1280 +- 230 (arg ~ -1846
//   +- 330), a kept tile needs a -5.4 sigma pair: ~all tiles skip.
// Common path per tile: 2 swizzled ds_read_b128 + 1 broadcast b128 (z2) +
// 2 chained MFMA + ~8 pk/max VALU + wave-uniform branch. No trans pipe, no
// long MFMA->exp2->fma dependency chain.
// Swizzle: byte colb ^= (row&7)<<4 on BOTH write and read (rule #21).
// C/D: col = lane&15 (x-col), row = 4*(lane>>4)+reg (z-row).
// ---------------------------------------------------------------------------
__global__ __launch_bounds__(1024) void igpr_fused(
        const float* __restrict__ x, const float* __restrict__ z,
        const float* __restrict__ alpha, const float* __restrict__ ls,
        float* __restrict__ out) {
    struct SM {
        uint4 zt[N_IND * 8];   // 1024 rows * 128 B = 128 KB (swizzled)
        float z2[N_IND];       // log2e * ||zw_i||^2
        float al[N_IND];       // alpha
        float wls[N_DESC];     // exp(-ls/2)
    };
    __shared__ SM sm;          // 136.25 KB of the CU's 160 KB

    const int tid  = threadIdx.x;
    const int lane = tid & 63;
    const int wave = tid >> 6;
    const int p = lane & 15;          // x-col within strip / D col
    const int g = lane >> 4;          // k-group; D rows 4g..4g+3 (z-rows)
    const int j = blockIdx.x * 256 + wave * 16 + p;   // this lane's x column

    if (tid < N_DESC) sm.wls[tid] = __expf(-0.5f * ls[tid]);
    __syncthreads();   // wls ready

    // ---- stage full z-panel into LDS (f32 -> weighted bf16, swizzled) ----
    {
        char* zb = reinterpret_cast<char*>(sm.zt);
#pragma unroll
        for (int rb = 0; rb < 8; ++rb) {
            int lb  = rb * 1024 + tid;       // 16B-output-granule index
            int row = lb >> 3, gr = lb & 7;  // z-row, granule in row
            float4 v0 = *reinterpret_cast<const float4*>(&z[row * 64 + gr * 8]);
            float4 v1 = *reinterpret_cast<const float4*>(&z[row * 64 + gr * 8 + 4]);
            float vv[8] = {v0.x, v0.y, v0.z, v0.w, v1.x, v1.y, v1.z, v1.w};
            ushort hb[8];
            float sq = 0.f;
#pragma unroll
            for (int e = 0; e < 8; ++e) {
                ushort h = f2bf(vv[e] * sm.wls[gr * 8 + e]);
                hb[e] = h;
                float vr = bf2f(h);
                sq = fmaf(vr, vr, sq);
            }
            uint4 u = make_uint4(
                (unsigned)hb[0] | ((unsigned)hb[1] << 16),
                (unsigned)hb[2] | ((unsigned)hb[3] << 16),
                (unsigned)hb[4] | ((unsigned)hb[5] << 16),
                (unsigned)hb[6] | ((unsigned)hb[7] << 16));
            int sw = row * 128 + ((gr * 16) ^ ((row & 7) << 4));
            *reinterpret_cast<uint4*>(zb + sw) = u;
            // row-sum over the 8 granule-lanes (xor partners within wave)
            sq += __shfl_xor(sq, 1);
            sq += __shfl_xor(sq, 2);
            sq += __shfl_xor(sq, 4);
            if (gr == 0) sm.z2[row] = sq * L2E;
        }
        sm.al[tid] = alpha[tid];   // N_IND == blockDim.x
    }

    // ---- B fragment (one 16-col strip) + log2e*x_sq, overlaps staging ----
    short8 b0, b1;
    float xs2;
    {
        const float* xr = x + (size_t)j * N_DESC;
        float sq = 0.f;
        short8 bb[2];
#pragma unroll
        for (int h = 0; h < 2; ++h) {
            float4 v0 = *reinterpret_cast<const float4*>(xr + h * 32 + g * 8);
            float4 v1 = *reinterpret_cast<const float4*>(xr + h * 32 + g * 8 + 4);
            float vv[8] = {v0.x, v0.y, v0.z, v0.w, v1.x, v1.y, v1.z, v1.w};
#pragma unroll
            for (int e = 0; e < 8; ++e) {
                ushort hh = f2bf(vv[e] * sm.wls[h * 32 + g * 8 + e]);
                bb[h][e] = (short)hh;
                float xv = bf2f(hh);
                sq = fmaf(xv, xv, sq);
            }
        }
        b0 = bb[0]; b1 = bb[1];
        sq += __shfl_xor(sq, 16);
        sq += __shfl_xor(sq, 32);
        xs2 = sq * L2E;
    }

    __syncthreads();   // z-panel ready (LDS read-only from here)

    const char* zb = reinterpret_cast<const char*>(sm.zt);
    const int rb0 = p * 128 + ((16 * g)      ^ ((p & 7) << 4));
    const int rb1 = p * 128 + ((64 + 16 * g) ^ ((p & 7) << 4));

    f32x2 accJ = {0.f, 0.f};
    const f32x2 xs2p = {xs2, xs2};

#pragma unroll 2
    for (int it = 0; it < TILES; ++it) {
        short8 a0 = *reinterpret_cast<const short8*>(zb + it * 2048 + rb0);
        short8 a1 = *reinterpret_cast<const short8*>(zb + it * 2048 + rb1);
        float4 z2 = *reinterpret_cast<const float4*>(&sm.z2[it * 16 + g * 4]);

        f32x4 t = {0.f, 0.f, 0.f, 0.f};
        t = __builtin_amdgcn_mfma_f32_16x16x32_bf16(a0, b0, t, 0, 0, 0);
        t = __builtin_amdgcn_mfma_f32_16x16x32_bf16(a1, b1, t, 0, 0, 0);

        f32x2 z2p0 = {z2.x, z2.y}, z2p1 = {z2.z, z2.w};
        f32x2 d0 = {t[0], t[1]}, d1 = {t[2], t[3]};
        f32x2 arg0 = d0 * L2E2 - (z2p0 + xs2p);    // pk_fma / pk_add
        f32x2 arg1 = d1 * L2E2 - (z2p1 + xs2p);
        float m = fmaxf(fmaxf(arg0.x, arg0.y), fmaxf(arg1.x, arg1.y));

        if (!__all(m < SKIP_THR)) {
            // rare path: a real contribution exists somewhere in this tile
            float4 a4 = *reinterpret_cast<const float4*>(&sm.al[it * 16 + g * 4]);
            f32x2 pv0 = {__builtin_amdgcn_exp2f(arg0.x),
                         __builtin_amdgcn_exp2f(arg0.y)};
            f32x2 pv1 = {__builtin_amdgcn_exp2f(arg1.x),
                         __builtin_amdgcn_exp2f(arg1.y)};
            f32x2 a4p0 = {a4.x, a4.y}, a4p1 = {a4.z, a4.w};
            accJ = accJ + a4p0 * pv0;              // pk_fma
            accJ = accJ + a4p1 * pv1;              // pk_fma
        }
    }

    float r = accJ.x + accJ.y;
    r += __shfl_xor(r, 16);
    r += __shfl_xor(r, 32);
    if (g == 0) out[j] = r;
}

extern "C" void kernel_launch(void* const* d_in, const int* in_sizes, int n_in,
                              void* d_out, int out_size, void* d_ws, size_t ws_size,
                              hipStream_t stream) {
    const float* x     = (const float*)d_in[0];   // (65536, 64)
    const float* z     = (const float*)d_in[1];   // (1024, 64)
    const float* alpha = (const float*)d_in[2];   // (1024,)
    const float* ls    = (const float*)d_in[3];   // (64,)
    float* out = (float*)d_out;                   // (65536, 1)

    igpr_fused<<<dim3(N_X / 256), dim3(1024), 0, stream>>>(x, z, alpha, ls, out);
}